// Round 4
// baseline (430.642 us; speedup 1.0000x reference)
//
#include <hip/hip_runtime.h>

#define DI __device__ __forceinline__

// ---------------- ws layout (float offsets), all 4-float aligned ----------------
// umax[8] (uint32) at 0:
//   [0]=|x| [1]=|act0| [2]=|act1| [3]=|act2| [4]=|act3| [5]=|act4|
constexpr int OFF_WSF0 = 8;
constexpr int OFF_BNS0 = 40;
constexpr int OFF_BNB0 = 72;
constexpr int OFF_W0I  = 104;    // 32*27 = 864
constexpr int OFF_WSF1 = 968;
constexpr int OFF_BNS1 = 972;
constexpr int OFF_BNB1 = 976;
constexpr int OFF_W1I  = 980;    // 4*32 = 128
constexpr int OFF_WSF2 = 1108;
constexpr int OFF_BNS2 = 1140;
constexpr int OFF_BNB2 = 1172;
constexpr int OFF_W2I  = 1204;   // 32*36 = 1152
constexpr int OFF_WSF3 = 2356;
constexpr int OFF_BNS3 = 2388;
constexpr int OFF_BNB3 = 2420;
constexpr int OFF_W3I  = 2452;   // 32*288 = 9216
constexpr int OFF_WSF4 = 11668;
constexpr int OFF_BNS4 = 11700;
constexpr int OFF_BNB4 = 11732;
constexpr int OFF_W4I  = 11764;  // 9216
constexpr int OFF_WSFD = 20980;  // 10
constexpr int OFF_WDI  = 20992;  // 10*2048 = 20480
constexpr int OFF_LOG  = 41472;  // 1024*10
constexpr int OFF_ACT  = 51712;
constexpr long ACT_A_OFF = OFF_ACT;              // act2/act4
constexpr long ACT_B_OFF = OFF_ACT + 8388608L;   // act1/act3

// ---------------- helpers ----------------
DI float quantv(float x, float sf) {
    float q = rintf(x / sf);
    return fminf(fmaxf(q, -127.0f), 127.0f);
}
DI float get_sf(const unsigned* umax, int slot) {
    return fmaxf(__uint_as_float(umax[slot]) / 127.0f, 1e-8f);
}
DI void wave_max_atomic(float v, unsigned* dst) {
    #pragma unroll
    for (int o = 32; o; o >>= 1) v = fmaxf(v, __shfl_down(v, o, 64));
    if ((threadIdx.x & 63) == 0) atomicMax(dst, __float_as_uint(v));
}

// ---------------- prep: weight quant + BN fold, all layers in one launch ----------------
struct PrepEntry {
    const float *w, *g, *bb, *m, *v;
    float *wsf, *wint, *bns, *bnb;
    int K; int has_bn;
};
struct PrepAll { PrepEntry e[6]; unsigned* umax; };

__global__ __launch_bounds__(256) void k_prep_all(PrepAll pa) {
    int blk = blockIdx.x;
    if (blk == 142) { if (threadIdx.x < 8) pa.umax[threadIdx.x] = 0u; return; }
    int layer, oc;
    if      (blk < 32)  { layer = 0; oc = blk; }
    else if (blk < 36)  { layer = 1; oc = blk - 32; }
    else if (blk < 68)  { layer = 2; oc = blk - 36; }
    else if (blk < 100) { layer = 3; oc = blk - 68; }
    else if (blk < 132) { layer = 4; oc = blk - 100; }
    else                { layer = 5; oc = blk - 132; }
    PrepEntry a = pa.e[layer];
    const float* wr = a.w + (long)oc * a.K;
    float mx = 0.f;
    for (int i = threadIdx.x; i < a.K; i += 256) mx = fmaxf(mx, fabsf(wr[i]));
    __shared__ float red[4];
    __shared__ float s_sf;
    #pragma unroll
    for (int o = 32; o; o >>= 1) mx = fmaxf(mx, __shfl_down(mx, o, 64));
    if ((threadIdx.x & 63) == 0) red[threadIdx.x >> 6] = mx;
    __syncthreads();
    if (threadIdx.x == 0) {
        float t = fmaxf(fmaxf(red[0], red[1]), fmaxf(red[2], red[3]));
        t = fmaxf(t / 127.0f, 1e-8f);
        a.wsf[oc] = t; s_sf = t;
        if (a.has_bn) {
            float inv = a.g[oc] / sqrtf(a.v[oc] + 1e-5f);
            a.bns[oc] = inv;
            a.bnb[oc] = a.bb[oc] - a.m[oc] * inv;
        }
    }
    __syncthreads();
    float sf = s_sf;
    for (int i = threadIdx.x; i < a.K; i += 256) a.wint[(long)oc * a.K + i] = rintf(wr[i] / sf);
}

__global__ __launch_bounds__(256) void k_absmax(const float4* __restrict__ x, int n4, unsigned* dst) {
    float m = 0.f;
    for (int i = blockIdx.x * blockDim.x + threadIdx.x; i < n4; i += gridDim.x * blockDim.x) {
        float4 t = x[i];
        m = fmaxf(m, fmaxf(fmaxf(fabsf(t.x), fabsf(t.y)), fmaxf(fabsf(t.z), fabsf(t.w))));
    }
    wave_max_atomic(m, dst);
}

// ---------------- conv0 machinery: padded tile [3][34][36] ----------------
DI void conv0_stage36(const float* xb, float sfx, float* tile) {
    for (int i = threadIdx.x; i < 3 * 34 * 36; i += 256) tile[i] = 0.f;
    __syncthreads();
    for (int i = threadIdx.x; i < 3072; i += 256) {
        int ci = i >> 10, px = i & 1023;
        int iy = px >> 5, ix = px & 31;
        tile[ci * 1224 + (iy + 1) * 36 + (ix + 1)] = quantv(xb[i], sfx);
    }
}
// window: 2 aligned b128 per (ci,row); elems 0..5 used for kx+dx
DI void conv0_win36(const float* tile, int h, int w0, float in[3][3][8]) {
    #pragma unroll
    for (int ci = 0; ci < 3; ++ci)
        #pragma unroll
        for (int r = 0; r < 3; ++r) {
            const float* rp = tile + ci * 1224 + (h + r) * 36 + w0;
            *(float4*)&in[ci][r][0] = *(const float4*)&rp[0];
            *(float4*)&in[ci][r][4] = *(const float4*)&rp[4];
        }
}

// pass 1: conv0+BN, global max only. grid = 2048 (image, oc-half)
__global__ __launch_bounds__(256) void k_conv0max(
    const float* __restrict__ x, const float* __restrict__ w0i,
    const float* __restrict__ wsf0, const float* __restrict__ bias0,
    const float* __restrict__ bns0, const float* __restrict__ bnb0,
    const unsigned* __restrict__ umax, unsigned* __restrict__ mout) {
    int b = blockIdx.x >> 1;
    int oc0 = (blockIdx.x & 1) * 16;
    __shared__ float tile[3 * 34 * 36];
    __shared__ float As[32], Cs[32];
    float sfx = get_sf(umax, 0);
    if (threadIdx.x < 32) {
        int oc = threadIdx.x;
        float bsf = wsf0[oc] * sfx;
        float bint = rintf(bias0[oc] / bsf);
        float a = bsf * bns0[oc];
        As[oc] = a;
        Cs[oc] = fmaf(bint, a, bnb0[oc]);
    }
    conv0_stage36(x + (long)b * 3072, sfx, tile);
    __syncthreads();
    int t = threadIdx.x;
    int h = t >> 3, w0 = (t & 7) * 4;
    float in[3][3][8];
    conv0_win36(tile, h, w0, in);
    float lmax = 0.f;
    #pragma unroll 2
    for (int o = 0; o < 16; ++o) {
        int oc = oc0 + o;
        const float* wp = w0i + oc * 27;   // uniform -> s_load
        float a0 = 0.f, a1 = 0.f, a2 = 0.f, a3 = 0.f;
        #pragma unroll
        for (int ci = 0; ci < 3; ++ci)
            #pragma unroll
            for (int ky = 0; ky < 3; ++ky)
                #pragma unroll
                for (int kx = 0; kx < 3; ++kx) {
                    float wv = wp[ci * 9 + ky * 3 + kx];
                    a0 = fmaf(in[ci][ky][kx + 0], wv, a0);
                    a1 = fmaf(in[ci][ky][kx + 1], wv, a1);
                    a2 = fmaf(in[ci][ky][kx + 2], wv, a2);
                    a3 = fmaf(in[ci][ky][kx + 3], wv, a3);
                }
        float A = As[oc], C = Cs[oc];
        lmax = fmaxf(lmax, fabsf(fmaf(a0, A, C)));
        lmax = fmaxf(lmax, fabsf(fmaf(a1, A, C)));
        lmax = fmaxf(lmax, fabsf(fmaf(a2, A, C)));
        lmax = fmaxf(lmax, fabsf(fmaf(a3, A, C)));
    }
    wave_max_atomic(lmax, mout);
}

// pass 2: recompute conv0 (identical FMA order) + quantize act0 + fused 1x1 conv1+BN
__global__ __launch_bounds__(256) void k_conv01(
    const float* __restrict__ x, const float* __restrict__ w0i,
    const float* __restrict__ wsf0, const float* __restrict__ bias0,
    const float* __restrict__ bns0, const float* __restrict__ bnb0,
    const float* __restrict__ w1i,
    const float* __restrict__ wsf1, const float* __restrict__ bias1,
    const float* __restrict__ bns1, const float* __restrict__ bnb1,
    const unsigned* __restrict__ umax, unsigned* __restrict__ mout,
    float* __restrict__ out) {
    int b = blockIdx.x;
    __shared__ float tile[3 * 34 * 36];
    __shared__ float As[32], Cs[32];
    __shared__ float A1s[4], C1s[4];
    float sfx = get_sf(umax, 0);
    float sf1 = get_sf(umax, 1);
    if (threadIdx.x < 32) {
        int oc = threadIdx.x;
        float bsf = wsf0[oc] * sfx;
        float bint = rintf(bias0[oc] / bsf);
        float a = bsf * bns0[oc];
        As[oc] = a;
        Cs[oc] = fmaf(bint, a, bnb0[oc]);
    }
    if (threadIdx.x >= 64 && threadIdx.x < 68) {
        int oc = threadIdx.x - 64;
        float bsf = wsf1[oc] * sf1;
        float bint = rintf(bias1[oc] / bsf);
        float a = bsf * bns1[oc];
        A1s[oc] = a;
        C1s[oc] = fmaf(bint, a, bnb1[oc]);
    }
    conv0_stage36(x + (long)b * 3072, sfx, tile);
    __syncthreads();
    int t = threadIdx.x;
    int h = t >> 3, w0 = (t & 7) * 4;
    float in[3][3][8];
    conv0_win36(tile, h, w0, in);
    float acc1[4][4] = {{0.f}};
    #pragma unroll 2
    for (int oc = 0; oc < 32; ++oc) {
        const float* wp = w0i + oc * 27;   // uniform -> s_load
        float a0 = 0.f, a1 = 0.f, a2 = 0.f, a3 = 0.f;
        #pragma unroll
        for (int ci = 0; ci < 3; ++ci)
            #pragma unroll
            for (int ky = 0; ky < 3; ++ky)
                #pragma unroll
                for (int kx = 0; kx < 3; ++kx) {
                    float wv = wp[ci * 9 + ky * 3 + kx];
                    a0 = fmaf(in[ci][ky][kx + 0], wv, a0);
                    a1 = fmaf(in[ci][ky][kx + 1], wv, a1);
                    a2 = fmaf(in[ci][ky][kx + 2], wv, a2);
                    a3 = fmaf(in[ci][ky][kx + 3], wv, a3);
                }
        float A = As[oc], C = Cs[oc];
        float q0 = quantv(fmaf(a0, A, C), sf1);
        float q1 = quantv(fmaf(a1, A, C), sf1);
        float q2 = quantv(fmaf(a2, A, C), sf1);
        float q3 = quantv(fmaf(a3, A, C), sf1);
        #pragma unroll
        for (int o1 = 0; o1 < 4; ++o1) {
            float wv1 = w1i[o1 * 32 + oc];   // uniform -> s_load
            acc1[o1][0] = fmaf(q0, wv1, acc1[o1][0]);
            acc1[o1][1] = fmaf(q1, wv1, acc1[o1][1]);
            acc1[o1][2] = fmaf(q2, wv1, acc1[o1][2]);
            acc1[o1][3] = fmaf(q3, wv1, acc1[o1][3]);
        }
    }
    float lmax = 0.f;
    float* ob = out + (long)b * 4096;
    #pragma unroll
    for (int o1 = 0; o1 < 4; ++o1) {
        float A = A1s[o1], C = C1s[o1];
        float4 res;
        float* rp = &res.x;
        #pragma unroll
        for (int dx = 0; dx < 4; ++dx) {
            float y = fmaf(acc1[o1][dx], A, C);
            rp[dx] = y;
            lmax = fmaxf(lmax, fabsf(y));
        }
        *(float4*)&ob[o1 * 1024 + h * 32 + w0] = res;
    }
    wave_max_atomic(lmax, mout);
}

// ---------------- conv2 (4->32, 3x3, s2, 32x32 -> 16x16) ----------------
// block = 1 image; tid = ocg(2b wave-id)<<6 | pxq; thread = 4px x 8oc. Weights via s_load.
__global__ __launch_bounds__(256) void k_conv2b(
    const float* __restrict__ inp, const float* __restrict__ wgl,
    const float* __restrict__ wsf, const float* __restrict__ bias,
    const float* __restrict__ bns, const float* __restrict__ bnb,
    const unsigned* __restrict__ umax, unsigned* __restrict__ mout,
    float* __restrict__ out) {
    constexpr int RS = 36, ROWS = 34;
    __shared__ float tile[4 * ROWS * RS];
    __shared__ float As[32], Cs[32];
    const int tid = threadIdx.x;
    const int ocg = __builtin_amdgcn_readfirstlane(tid >> 6);  // wave-uniform
    const int pxq = tid & 63;
    const int h = pxq >> 2, c = pxq & 3;
    float sf = get_sf(umax, 2);
    if (tid < 32) {
        int oc = tid;
        float bsf = wsf[oc] * sf;
        float bint = rintf(bias[oc] / bsf);
        float a = bsf * bns[oc];
        As[oc] = a;
        Cs[oc] = fmaf(bint, a, bnb[oc]);
    }
    for (int i = tid; i < 4 * ROWS * RS; i += 256) tile[i] = 0.f;
    __syncthreads();
    const float* ib = inp + (long)blockIdx.x * 4096;
    for (int i = tid; i < 4096; i += 256) {
        int ci = i >> 10, px = i & 1023;
        int iy = px >> 5, ix = px & 31;
        tile[ci * (ROWS * RS) + (iy + 1) * RS + (ix + 1)] = quantv(ib[i], sf);
    }
    __syncthreads();
    float acc[32];
    #pragma unroll
    for (int i = 0; i < 32; ++i) acc[i] = 0.f;
    #pragma unroll
    for (int ci = 0; ci < 4; ++ci) {
        float win[3][12];
        #pragma unroll
        for (int ky = 0; ky < 3; ++ky) {
            const float* rp = tile + ci * (ROWS * RS) + (2 * h + ky) * RS + 8 * c;
            #pragma unroll
            for (int d = 0; d < 3; ++d)
                *(float4*)&win[ky][4 * d] = *(const float4*)&rp[4 * d];
        }
        #pragma unroll
        for (int k = 0; k < 8; ++k) {
            const float* wp = wgl + (ocg * 8 + k) * 36 + ci * 9;  // uniform -> s_load
            #pragma unroll
            for (int j = 0; j < 9; ++j) {
                float wv = wp[j];
                int ky = j / 3, kx = j % 3;
                #pragma unroll
                for (int px = 0; px < 4; ++px)
                    acc[k * 4 + px] = fmaf(win[ky][2 * px + kx], wv, acc[k * 4 + px]);
            }
        }
    }
    float lmax = 0.f;
    float* ob = out + (long)blockIdx.x * 8192;
    #pragma unroll
    for (int k = 0; k < 8; ++k) {
        int oc = ocg * 8 + k;
        float A = As[oc], C = Cs[oc];
        float4 r;
        float* rp = &r.x;
        #pragma unroll
        for (int px = 0; px < 4; ++px) {
            float y = fmaf(acc[k * 4 + px], A, C);
            rp[px] = y;
            lmax = fmaxf(lmax, fabsf(y));
        }
        *(float4*)&ob[oc * 256 + h * 16 + c * 4] = r;
    }
    wave_max_atomic(lmax, mout);
}

// ---------------- conv3/conv4 (32->32, 3x3, out 8x8) ----------------
// block = 2 images; wave = (img, oc-half); lane = out pixel. acc[16]. Weights via s_load.
template<int HIN, int S, int NPH>
__global__ __launch_bounds__(256) void k_conv34c(
    const float* __restrict__ inp, const float* __restrict__ wgl,
    const float* __restrict__ wsf, const float* __restrict__ bias,
    const float* __restrict__ bns, const float* __restrict__ bnb,
    const unsigned* __restrict__ umax, int slot, unsigned* __restrict__ mout,
    float* __restrict__ out) {
    constexpr int ROWS = HIN + 2;
    constexpr int RS   = (S == 2) ? 20 : 12;
    constexpr int CIPP = 32 / NPH;
    constexpr int PIX  = HIN * HIN;
    constexpr int TILE = 2 * CIPP * ROWS * RS;
    constexpr int NELT = 2 * CIPP * PIX;
    __shared__ float tile[TILE];
    __shared__ float As[32], Cs[32];
    const int tid = threadIdx.x;
    const int lane = tid & 63;
    const int imgl  = __builtin_amdgcn_readfirstlane(tid >> 7);
    const int ohalf = __builtin_amdgcn_readfirstlane((tid >> 6) & 1);
    const int h = lane >> 3, w = lane & 7;
    const float sf = get_sf(umax, slot);
    if (tid < 32) {
        int oc = tid;
        float bsf = wsf[oc] * sf;
        float bint = rintf(bias[oc] / bsf);
        float a = bsf * bns[oc];
        As[oc] = a;
        Cs[oc] = fmaf(bint, a, bnb[oc]);
    }
    for (int i = tid; i < TILE; i += 256) tile[i] = 0.f;
    float acc[16];
    #pragma unroll
    for (int i = 0; i < 16; ++i) acc[i] = 0.f;
    const float* ib = inp + (long)blockIdx.x * 2 * 32 * PIX;
    for (int ph = 0; ph < NPH; ++ph) {
        __syncthreads();
        for (int i = tid; i < NELT; i += 256) {
            int im = i / (CIPP * PIX);          // power-of-2 -> shift
            int ci = (i / PIX) & (CIPP - 1);
            int px = i & (PIX - 1);
            int iy = px / HIN, ix = px & (HIN - 1);
            tile[(im * CIPP + ci) * (ROWS * RS) + (iy + 1) * RS + (ix + 1)] =
                quantv(ib[(long)(im * 32 + ph * CIPP + ci) * PIX + px], sf);
        }
        __syncthreads();
        const float* tb = tile + imgl * CIPP * (ROWS * RS);
        #pragma unroll 2
        for (int ci = 0; ci < CIPP; ++ci) {
            float tv[9];
            #pragma unroll
            for (int ky = 0; ky < 3; ++ky)
                #pragma unroll
                for (int kx = 0; kx < 3; ++kx)
                    tv[ky * 3 + kx] = tb[ci * (ROWS * RS) + (S * h + ky) * RS + (S * w + kx)];
            #pragma unroll
            for (int k = 0; k < 16; ++k) {
                const float* wp = wgl + (ohalf * 16 + k) * 288 + (ph * CIPP + ci) * 9; // s_load
                #pragma unroll
                for (int j = 0; j < 9; ++j)
                    acc[k] = fmaf(tv[j], wp[j], acc[k]);
            }
        }
    }
    float lmax = 0.f;
    long imgg = (long)blockIdx.x * 2 + imgl;
    #pragma unroll
    for (int k = 0; k < 16; ++k) {
        int oc = ohalf * 16 + k;
        float y = fmaf(acc[k], As[oc], Cs[oc]);
        out[(imgg * 32 + oc) * 64 + lane] = y;
        lmax = fmaxf(lmax, fabsf(y));
    }
    wave_max_atomic(lmax, mout);
}

// linear 2048->10 per image
__global__ __launch_bounds__(256) void k_fc(
    const float* __restrict__ act, const float* __restrict__ wdi,
    const float* __restrict__ wsfd, const float* __restrict__ bd,
    const unsigned* __restrict__ umax, float* __restrict__ logits) {
    int b = blockIdx.x;
    float sf = get_sf(umax, 5);
    const float* ab = act + (long)b * 2048;
    float acc[10] = {0.f, 0.f, 0.f, 0.f, 0.f, 0.f, 0.f, 0.f, 0.f, 0.f};
    #pragma unroll
    for (int k = 0; k < 8; ++k) {
        int j = threadIdx.x + 256 * k;
        float q = quantv(ab[j], sf);
        #pragma unroll
        for (int c = 0; c < 10; ++c) acc[c] = fmaf(q, wdi[c * 2048 + j], acc[c]);
    }
    #pragma unroll
    for (int c = 0; c < 10; ++c)
        #pragma unroll
        for (int o = 32; o; o >>= 1) acc[c] += __shfl_down(acc[c], o, 64);
    __shared__ float red[4][10];
    int wid = threadIdx.x >> 6;
    if ((threadIdx.x & 63) == 0)
        #pragma unroll
        for (int c = 0; c < 10; ++c) red[wid][c] = acc[c];
    __syncthreads();
    if (threadIdx.x < 10) {
        int c = threadIdx.x;
        float s = red[0][c] + red[1][c] + red[2][c] + red[3][c];
        float bsf = wsfd[c] * sf;
        float bint = rintf(bd[c] / bsf);
        logits[b * 10 + c] = (s + bint) * bsf;
    }
}

// softmax over batch axis (dim 0). one block per class column
__global__ __launch_bounds__(256) void k_softmax(const float* __restrict__ logits, float* __restrict__ out) {
    int c = blockIdx.x;
    float v[4];
    #pragma unroll
    for (int k = 0; k < 4; ++k) v[k] = logits[(threadIdx.x + 256 * k) * 10 + c];
    float mx = fmaxf(fmaxf(v[0], v[1]), fmaxf(v[2], v[3]));
    __shared__ float redm[4];
    __shared__ float reds[4];
    #pragma unroll
    for (int o = 32; o; o >>= 1) mx = fmaxf(mx, __shfl_down(mx, o, 64));
    if ((threadIdx.x & 63) == 0) redm[threadIdx.x >> 6] = mx;
    __syncthreads();
    mx = fmaxf(fmaxf(redm[0], redm[1]), fmaxf(redm[2], redm[3]));
    float e[4], s = 0.f;
    #pragma unroll
    for (int k = 0; k < 4; ++k) { e[k] = expf(v[k] - mx); s += e[k]; }
    #pragma unroll
    for (int o = 32; o; o >>= 1) s += __shfl_down(s, o, 64);
    if ((threadIdx.x & 63) == 0) reds[threadIdx.x >> 6] = s;
    __syncthreads();
    s = reds[0] + reds[1] + reds[2] + reds[3];
    #pragma unroll
    for (int k = 0; k < 4; ++k) out[(threadIdx.x + 256 * k) * 10 + c] = e[k] / s;
}

extern "C" void kernel_launch(void* const* d_in, const int* in_sizes, int n_in,
                              void* d_out, int out_size, void* d_ws, size_t ws_size,
                              hipStream_t stream) {
    (void)in_sizes; (void)n_in; (void)out_size; (void)ws_size;
    const float* x = (const float*)d_in[0];
    const float *w[5], *bia[5], *g[5], *bb[5], *m[5], *v[5];
    for (int i = 0; i < 5; ++i) {
        w[i]   = (const float*)d_in[1 + 6 * i + 0];
        bia[i] = (const float*)d_in[1 + 6 * i + 1];
        g[i]   = (const float*)d_in[1 + 6 * i + 2];
        bb[i]  = (const float*)d_in[1 + 6 * i + 3];
        m[i]   = (const float*)d_in[1 + 6 * i + 4];
        v[i]   = (const float*)d_in[1 + 6 * i + 5];
    }
    const float* wd = (const float*)d_in[31];
    const float* bd = (const float*)d_in[32];
    float* ws = (float*)d_ws;
    unsigned* umax = (unsigned*)ws;
    float* out = (float*)d_out;

    float* wsf0 = ws + OFF_WSF0; float* bns0 = ws + OFF_BNS0; float* bnb0 = ws + OFF_BNB0; float* w0i = ws + OFF_W0I;
    float* wsf1 = ws + OFF_WSF1; float* bns1 = ws + OFF_BNS1; float* bnb1 = ws + OFF_BNB1; float* w1i = ws + OFF_W1I;
    float* wsf2 = ws + OFF_WSF2; float* bns2 = ws + OFF_BNS2; float* bnb2 = ws + OFF_BNB2; float* w2i = ws + OFF_W2I;
    float* wsf3 = ws + OFF_WSF3; float* bns3 = ws + OFF_BNS3; float* bnb3 = ws + OFF_BNB3; float* w3i = ws + OFF_W3I;
    float* wsf4 = ws + OFF_WSF4; float* bns4 = ws + OFF_BNS4; float* bnb4 = ws + OFF_BNB4; float* w4i = ws + OFF_W4I;
    float* wsfd = ws + OFF_WSFD; float* wdi = ws + OFF_WDI;
    float* logits = ws + OFF_LOG;
    float* actA = ws + ACT_A_OFF;   // act2 / act4
    float* actB = ws + ACT_B_OFF;   // act1 / act3

    PrepAll pa;
    pa.umax = umax;
    const float* ww[6] = {w[0], w[1], w[2], w[3], w[4], wd};
    float* wsfp[6] = {wsf0, wsf1, wsf2, wsf3, wsf4, wsfd};
    float* wip[6]  = {w0i, w1i, w2i, w3i, w4i, wdi};
    float* bnsp[6] = {bns0, bns1, bns2, bns3, bns4, nullptr};
    float* bnbp[6] = {bnb0, bnb1, bnb2, bnb3, bnb4, nullptr};
    int Ks[6] = {27, 32, 36, 288, 288, 2048};
    for (int i = 0; i < 6; ++i) {
        pa.e[i].w = ww[i];
        pa.e[i].g = (i < 5) ? g[i] : nullptr;
        pa.e[i].bb = (i < 5) ? bb[i] : nullptr;
        pa.e[i].m = (i < 5) ? m[i] : nullptr;
        pa.e[i].v = (i < 5) ? v[i] : nullptr;
        pa.e[i].wsf = wsfp[i];
        pa.e[i].wint = wip[i];
        pa.e[i].bns = bnsp[i];
        pa.e[i].bnb = bnbp[i];
        pa.e[i].K = Ks[i];
        pa.e[i].has_bn = (i < 5) ? 1 : 0;
    }

    hipLaunchKernelGGL(k_prep_all, dim3(143), dim3(256), 0, stream, pa);
    hipLaunchKernelGGL(k_absmax, dim3(1024), dim3(256), 0, stream,
                       (const float4*)x, 1024 * 3 * 32 * 32 / 4, umax + 0);
    hipLaunchKernelGGL(k_conv0max, dim3(2048), dim3(256), 0, stream,
                       x, w0i, wsf0, bia[0], bns0, bnb0, umax, umax + 1);
    hipLaunchKernelGGL(k_conv01, dim3(1024), dim3(256), 0, stream,
                       x, w0i, wsf0, bia[0], bns0, bnb0,
                       w1i, wsf1, bia[1], bns1, bnb1, umax, umax + 2, actB);
    hipLaunchKernelGGL(k_conv2b, dim3(1024), dim3(256), 0, stream,
                       actB, w2i, wsf2, bia[2], bns2, bnb2, umax, umax + 3, actA);
    hipLaunchKernelGGL((k_conv34c<16, 2, 2>), dim3(512), dim3(256), 0, stream,
                       actA, w3i, wsf3, bia[3], bns3, bnb3, umax, 3, umax + 4, actB);
    hipLaunchKernelGGL((k_conv34c<8, 1, 1>),  dim3(512), dim3(256), 0, stream,
                       actB, w4i, wsf4, bia[4], bns4, bnb4, umax, 4, umax + 5, actA);
    hipLaunchKernelGGL(k_fc, dim3(1024), dim3(256), 0, stream, actA, wdi, wsfd, bd, umax, logits);
    hipLaunchKernelGGL(k_softmax, dim3(10), dim3(256), 0, stream, logits, out);
}

// Round 5
// 233.218 us; speedup vs baseline: 1.8465x; 1.8465x over previous
//
#include <hip/hip_runtime.h>

#define DI __device__ __forceinline__

// ---------------- ws layout (float offsets) ----------------
// umax[8] (uint32) at 0: [0]=|x| [1]=|act0| [2]=|act1| [3]=|act2| [4]=|act3| [5]=|act4|
constexpr int OFF_WSF0 = 8;
constexpr int OFF_BNS0 = 40;
constexpr int OFF_BNB0 = 72;
constexpr int OFF_W0I  = 104;    // 32*27
constexpr int OFF_WSF1 = 968;
constexpr int OFF_BNS1 = 972;
constexpr int OFF_BNB1 = 976;
constexpr int OFF_W1I  = 980;    // 4*32
constexpr int OFF_WSF2 = 1108;
constexpr int OFF_BNS2 = 1140;
constexpr int OFF_BNB2 = 1172;
constexpr int OFF_W2I  = 1204;   // 32*36
constexpr int OFF_WSF3 = 2356;
constexpr int OFF_BNS3 = 2388;
constexpr int OFF_BNB3 = 2420;
constexpr int OFF_W3I  = 2452;   // 32*288
constexpr int OFF_WSF4 = 11668;
constexpr int OFF_BNS4 = 11700;
constexpr int OFF_BNB4 = 11732;
constexpr int OFF_W4I  = 11764;  // 9216
constexpr int OFF_WSFD = 20980;  // 10
constexpr int OFF_WDI  = 20992;  // 20480
constexpr int OFF_LOG  = 41472;  // 10240
constexpr int OFF_ACT  = 51712;
constexpr long ACT_A_OFF = OFF_ACT;              // act2/act4
constexpr long ACT_B_OFF = OFF_ACT + 8388608L;   // act1/act3

// ---------------- helpers ----------------
DI float quantv(float x, float sf) {
    float q = rintf(x / sf);
    return fminf(fmaxf(q, -127.0f), 127.0f);
}
DI float get_sf(const unsigned* umax, int slot) {
    return fmaxf(__uint_as_float(umax[slot]) / 127.0f, 1e-8f);
}
DI void block_max_atomic(float v, unsigned* dst) {
    __shared__ float redm_[4];
    #pragma unroll
    for (int o = 32; o; o >>= 1) v = fmaxf(v, __shfl_down(v, o, 64));
    int wid = threadIdx.x >> 6;
    if ((threadIdx.x & 63) == 0) redm_[wid] = v;
    __syncthreads();
    if (threadIdx.x == 0) {
        int nw = blockDim.x >> 6;
        float m = redm_[0];
        for (int i = 1; i < nw; ++i) m = fmaxf(m, redm_[i]);
        atomicMax(dst, __float_as_uint(m));
    }
}

// ---------------- prep: weight quant + BN fold ----------------
struct PrepEntry {
    const float *w, *g, *bb, *m, *v;
    float *wsf, *wint, *bns, *bnb;
    int K; int has_bn;
};
struct PrepAll { PrepEntry e[6]; unsigned* umax; };

__global__ __launch_bounds__(256) void k_prep_all(PrepAll pa) {
    int blk = blockIdx.x;
    if (blk == 142) { if (threadIdx.x < 8) pa.umax[threadIdx.x] = 0u; return; }
    int layer, oc;
    if      (blk < 32)  { layer = 0; oc = blk; }
    else if (blk < 36)  { layer = 1; oc = blk - 32; }
    else if (blk < 68)  { layer = 2; oc = blk - 36; }
    else if (blk < 100) { layer = 3; oc = blk - 68; }
    else if (blk < 132) { layer = 4; oc = blk - 100; }
    else                { layer = 5; oc = blk - 132; }
    PrepEntry a = pa.e[layer];
    const float* wr = a.w + (long)oc * a.K;
    float mx = 0.f;
    for (int i = threadIdx.x; i < a.K; i += 256) mx = fmaxf(mx, fabsf(wr[i]));
    __shared__ float red[4];
    __shared__ float s_sf;
    #pragma unroll
    for (int o = 32; o; o >>= 1) mx = fmaxf(mx, __shfl_down(mx, o, 64));
    if ((threadIdx.x & 63) == 0) red[threadIdx.x >> 6] = mx;
    __syncthreads();
    if (threadIdx.x == 0) {
        float t = fmaxf(fmaxf(red[0], red[1]), fmaxf(red[2], red[3]));
        t = fmaxf(t / 127.0f, 1e-8f);
        a.wsf[oc] = t; s_sf = t;
        if (a.has_bn) {
            float inv = a.g[oc] / sqrtf(a.v[oc] + 1e-5f);
            a.bns[oc] = inv;
            a.bnb[oc] = a.bb[oc] - a.m[oc] * inv;
        }
    }
    __syncthreads();
    float sf = s_sf;
    for (int i = threadIdx.x; i < a.K; i += 256) a.wint[(long)oc * a.K + i] = rintf(wr[i] / sf);
}

__global__ __launch_bounds__(256) void k_absmax(const float4* __restrict__ x, int n4, unsigned* dst) {
    float m = 0.f;
    for (int i = blockIdx.x * blockDim.x + threadIdx.x; i < n4; i += gridDim.x * blockDim.x) {
        float4 t = x[i];
        m = fmaxf(m, fmaxf(fmaxf(fabsf(t.x), fabsf(t.y)), fmaxf(fabsf(t.z), fabsf(t.w))));
    }
    block_max_atomic(m, dst);
}

// ---------------- conv0 pass 1: max only. grid 2048 = (image, row-half) ----------------
// thread = 4 oc x 16 px. LDS: tile[3][18][36] (rows r0-1..r0+16), weights k-major [27][32].
__global__ __launch_bounds__(256) void k_conv0maxN(
    const float* __restrict__ x, const float* __restrict__ w0i,
    const float* __restrict__ wsf0, const float* __restrict__ bias0,
    const float* __restrict__ bns0, const float* __restrict__ bnb0,
    const unsigned* __restrict__ umax, unsigned* __restrict__ mout) {
    __shared__ float tile[3 * 18 * 36];   // 1944
    __shared__ float wlds[27 * 32];       // 864
    __shared__ float As[32], Cs[32];
    const int b  = blockIdx.x >> 1;
    const int r0 = (blockIdx.x & 1) * 16;
    const int tid = threadIdx.x;
    const float sfx = get_sf(umax, 0);
    if (tid < 32) {
        int oc = tid;
        float bsf = wsf0[oc] * sfx;
        float bint = rintf(bias0[oc] / bsf);
        float a = bsf * bns0[oc];
        As[oc] = a;
        Cs[oc] = fmaf(bint, a, bnb0[oc]);
    }
    for (int i = tid; i < 1944; i += 256) tile[i] = 0.f;
    for (int i = tid; i < 864; i += 256) {
        int k = i >> 5, oc = i & 31;
        wlds[i] = w0i[oc * 27 + k];
    }
    __syncthreads();
    const float* xb = x + (long)b * 3072;
    for (int i = tid; i < 1728; i += 256) {          // 3 ci * 18 rows * 32 cols
        int ci = i / 576, rem = i - ci * 576;
        int rr = rem >> 5, cc = rem & 31;
        int gr = r0 - 1 + rr;
        if ((unsigned)gr < 32u)
            tile[ci * 648 + rr * 36 + cc + 1] = quantv(xb[ci * 1024 + gr * 32 + cc], sfx);
    }
    __syncthreads();
    const int oc0  = (tid >> 5) * 4;       // 8 oc-quads
    const int pxg  = tid & 31;
    const int row  = pxg >> 1;             // 0..15 (output row r0+row)
    const int wcol = (pxg & 1) * 16;       // output col base
    float acc[4][16];
    #pragma unroll
    for (int o = 0; o < 4; ++o)
        #pragma unroll
        for (int p = 0; p < 16; ++p) acc[o][p] = 0.f;
    #pragma unroll 1
    for (int kk = 0; kk < 9; ++kk) {       // kk = ci*3 + ky
        int ci = kk / 3, ky = kk - ci * 3;
        const float* rp = tile + ci * 648 + (row + ky) * 36 + wcol;
        float wn[20];
        #pragma unroll
        for (int d = 0; d < 5; ++d) *(float4*)&wn[4 * d] = *(const float4*)&rp[4 * d];
        #pragma unroll
        for (int kx = 0; kx < 3; ++kx) {
            float4 wv = *(const float4*)&wlds[(kk * 3 + kx) * 32 + oc0];
            const float* wf = &wv.x;
            #pragma unroll
            for (int o = 0; o < 4; ++o)
                #pragma unroll
                for (int p = 0; p < 16; ++p)
                    acc[o][p] = fmaf(wn[p + kx], wf[o], acc[o][p]);
        }
    }
    float lmax = 0.f;
    #pragma unroll
    for (int o = 0; o < 4; ++o) {
        float A = As[oc0 + o], C = Cs[oc0 + o];
        #pragma unroll
        for (int p = 0; p < 16; ++p)
            lmax = fmaxf(lmax, fabsf(fmaf(acc[o][p], A, C)));
    }
    block_max_atomic(lmax, mout);
}

// ---------------- conv0 pass 2 + fused 1x1 conv1. grid 512 = B/2 ----------------
// thread = 8 px, all 32 oc sequential; window cached in 108 registers.
__global__ __launch_bounds__(256) void k_conv01n(
    const float* __restrict__ x, const float* __restrict__ w0i,
    const float* __restrict__ wsf0, const float* __restrict__ bias0,
    const float* __restrict__ bns0, const float* __restrict__ bnb0,
    const float* __restrict__ w1i,
    const float* __restrict__ wsf1, const float* __restrict__ bias1,
    const float* __restrict__ bns1, const float* __restrict__ bnb1,
    const unsigned* __restrict__ umax, unsigned* __restrict__ mout,
    float* __restrict__ out) {
    __shared__ float tile[2 * 3672];      // [img][3][34][36]
    __shared__ float wls0[896];           // [32][28]
    __shared__ float wls1[128];           // [32][4]
    __shared__ float As[32], Cs[32];
    __shared__ float A1s[4], C1s[4];
    const int tid = threadIdx.x;
    const long b2 = (long)blockIdx.x * 2;
    const float sfx = get_sf(umax, 0);
    const float sf1 = get_sf(umax, 1);
    if (tid < 32) {
        int oc = tid;
        float bsf = wsf0[oc] * sfx;
        float bint = rintf(bias0[oc] / bsf);
        float a = bsf * bns0[oc];
        As[oc] = a;
        Cs[oc] = fmaf(bint, a, bnb0[oc]);
    }
    if (tid >= 64 && tid < 68) {
        int oc = tid - 64;
        float bsf = wsf1[oc] * sf1;
        float bint = rintf(bias1[oc] / bsf);
        float a = bsf * bns1[oc];
        A1s[oc] = a;
        C1s[oc] = fmaf(bint, a, bnb1[oc]);
    }
    for (int i = tid; i < 2 * 3672; i += 256) tile[i] = 0.f;
    for (int i = tid; i < 864; i += 256) {
        int oc = i / 27, k = i - oc * 27;
        wls0[oc * 28 + k] = w0i[i];
    }
    if (tid < 128) {
        int o1 = tid >> 5, oc = tid & 31;
        wls1[oc * 4 + o1] = w1i[tid];
    }
    __syncthreads();
    for (int i = tid; i < 6144; i += 256) {
        int img = i / 3072, rem = i - img * 3072;
        int ci = rem >> 10, px = rem & 1023;
        int iy = px >> 5, ix = px & 31;
        tile[img * 3672 + ci * 1224 + (iy + 1) * 36 + (ix + 1)] =
            quantv(x[(b2 + img) * 3072 + rem], sfx);
    }
    __syncthreads();
    const int img = tid >> 7;
    const int pt  = tid & 127;
    const int h   = pt >> 2;          // out row 0..31
    const int w0  = (pt & 3) * 8;     // out col base
    // cache the full 3x3x(8+2) window in registers
    float win[3][3][12];
    #pragma unroll
    for (int ci = 0; ci < 3; ++ci)
        #pragma unroll
        for (int ky = 0; ky < 3; ++ky) {
            const float* rp = tile + img * 3672 + ci * 1224 + (h + ky) * 36 + w0;
            #pragma unroll
            for (int d = 0; d < 3; ++d)
                *(float4*)&win[ci][ky][4 * d] = *(const float4*)&rp[4 * d];
        }
    float acc1[4][8];
    #pragma unroll
    for (int o = 0; o < 4; ++o)
        #pragma unroll
        for (int p = 0; p < 8; ++p) acc1[o][p] = 0.f;
    #pragma unroll 1
    for (int oc = 0; oc < 32; ++oc) {
        float wreg[28];
        const float4* wp4 = (const float4*)&wls0[oc * 28];
        #pragma unroll
        for (int d = 0; d < 7; ++d) *(float4*)&wreg[4 * d] = wp4[d];
        float acc0[8];
        #pragma unroll
        for (int p = 0; p < 8; ++p) acc0[p] = 0.f;
        #pragma unroll
        for (int ci = 0; ci < 3; ++ci)
            #pragma unroll
            for (int ky = 0; ky < 3; ++ky)
                #pragma unroll
                for (int kx = 0; kx < 3; ++kx) {
                    float wv = wreg[ci * 9 + ky * 3 + kx];
                    #pragma unroll
                    for (int p = 0; p < 8; ++p)
                        acc0[p] = fmaf(win[ci][ky][p + kx], wv, acc0[p]);
                }
        float A = As[oc], C = Cs[oc];
        float4 w1v = *(const float4*)&wls1[oc * 4];
        const float* w1f = &w1v.x;
        #pragma unroll
        for (int p = 0; p < 8; ++p) {
            float q = quantv(fmaf(acc0[p], A, C), sf1);
            #pragma unroll
            for (int o = 0; o < 4; ++o)
                acc1[o][p] = fmaf(q, w1f[o], acc1[o][p]);
        }
    }
    float lmax = 0.f;
    float* ob = out + (b2 + img) * 4096;
    #pragma unroll
    for (int o = 0; o < 4; ++o) {
        float A = A1s[o], C = C1s[o];
        float r[8];
        #pragma unroll
        for (int p = 0; p < 8; ++p) {
            float y = fmaf(acc1[o][p], A, C);
            r[p] = y;
            lmax = fmaxf(lmax, fabsf(y));
        }
        *(float4*)&ob[o * 1024 + h * 32 + w0]     = *(float4*)&r[0];
        *(float4*)&ob[o * 1024 + h * 32 + w0 + 4] = *(float4*)&r[4];
    }
    block_max_atomic(lmax, mout);
}

// ---------------- conv2 (4->32, 3x3, s2): thread = 8 oc x 4 px, weights k-major LDS ----------------
__global__ __launch_bounds__(256) void k_conv2c(
    const float* __restrict__ inp, const float* __restrict__ wgl,
    const float* __restrict__ wsf, const float* __restrict__ bias,
    const float* __restrict__ bns, const float* __restrict__ bnb,
    const unsigned* __restrict__ umax, unsigned* __restrict__ mout,
    float* __restrict__ out) {
    __shared__ float tile[4 * 34 * 36];   // 4896
    __shared__ float wlds[36 * 32];       // 1152, k-major
    __shared__ float As[32], Cs[32];
    const int tid = threadIdx.x;
    const float sf = get_sf(umax, 2);
    if (tid < 32) {
        int oc = tid;
        float bsf = wsf[oc] * sf;
        float bint = rintf(bias[oc] / bsf);
        float a = bsf * bns[oc];
        As[oc] = a;
        Cs[oc] = fmaf(bint, a, bnb[oc]);
    }
    for (int i = tid; i < 4896; i += 256) tile[i] = 0.f;
    for (int i = tid; i < 1152; i += 256) {
        int k = i >> 5, oc = i & 31;
        wlds[i] = wgl[oc * 36 + k];
    }
    __syncthreads();
    const float* ib = inp + (long)blockIdx.x * 4096;
    for (int i = tid; i < 4096; i += 256) {
        int ci = i >> 10, px = i & 1023;
        int iy = px >> 5, ix = px & 31;
        tile[ci * 1224 + (iy + 1) * 36 + (ix + 1)] = quantv(ib[i], sf);
    }
    __syncthreads();
    const int oc0 = (tid >> 6) * 8;
    const int pxq = tid & 63;
    const int h = pxq >> 2, c = pxq & 3;   // out row h, cols 4c..4c+3
    float acc[8][4];
    #pragma unroll
    for (int k = 0; k < 8; ++k)
        #pragma unroll
        for (int p = 0; p < 4; ++p) acc[k][p] = 0.f;
    #pragma unroll 1
    for (int ci = 0; ci < 4; ++ci) {
        #pragma unroll
        for (int ky = 0; ky < 3; ++ky) {
            const float* rp = tile + ci * 1224 + (2 * h + ky) * 36 + 8 * c;
            float wn[12];
            #pragma unroll
            for (int d = 0; d < 3; ++d) *(float4*)&wn[4 * d] = *(const float4*)&rp[4 * d];
            #pragma unroll
            for (int kx = 0; kx < 3; ++kx) {
                const float* wp = &wlds[(ci * 9 + ky * 3 + kx) * 32 + oc0];
                float4 wa = *(const float4*)&wp[0];
                float4 wb = *(const float4*)&wp[4];
                float wf[8] = {wa.x, wa.y, wa.z, wa.w, wb.x, wb.y, wb.z, wb.w};
                #pragma unroll
                for (int k = 0; k < 8; ++k)
                    #pragma unroll
                    for (int p = 0; p < 4; ++p)
                        acc[k][p] = fmaf(wn[2 * p + kx], wf[k], acc[k][p]);
            }
        }
    }
    float lmax = 0.f;
    float* ob = out + (long)blockIdx.x * 8192;
    #pragma unroll
    for (int k = 0; k < 8; ++k) {
        int oc = oc0 + k;
        float A = As[oc], C = Cs[oc];
        float4 r;
        float* rp = &r.x;
        #pragma unroll
        for (int p = 0; p < 4; ++p) {
            float y = fmaf(acc[k][p], A, C);
            rp[p] = y;
            lmax = fmaxf(lmax, fabsf(y));
        }
        *(float4*)&ob[oc * 256 + h * 16 + c * 4] = r;
    }
    block_max_atomic(lmax, mout);
}

// ---------------- conv3/conv4 (R3-proven): 2 img/block, 4oc x 4px, K-phased LDS ----------------
template<int HIN, int S>
__global__ __launch_bounds__(256) void k_conv34b(
    const float* __restrict__ inp, const float* __restrict__ wi,
    const float* __restrict__ wsf, const float* __restrict__ bias,
    const float* __restrict__ bns, const float* __restrict__ bnb,
    const unsigned* __restrict__ umax, int slot, unsigned* __restrict__ mout,
    float* __restrict__ out) {
    constexpr int ROWS = HIN + 2;
    constexpr int RS   = (S == 2) ? 20 : 12;
    constexpr int TI   = 8 * ROWS * RS;
    constexpr int PIX  = HIN * HIN;
    constexpr int NELT = 2 * 8 * PIX;
    constexpr int WINW = (S == 2) ? 12 : 8;
    constexpr int ND   = (S == 2) ? 3 : 2;
    __shared__ float tile[2 * TI];
    __shared__ float wlds[72 * 36];
    __shared__ float As[32], Cs[32];
    const int tid  = threadIdx.x;
    const int imgl = tid >> 7;
    const int ocg  = (tid >> 4) & 7;
    const int pxq  = tid & 15;
    const int h = pxq >> 1, c = pxq & 1;
    const float sf = get_sf(umax, slot);
    if (tid < 32) {
        int oc = tid;
        float bsf = wsf[oc] * sf;
        float bint = rintf(bias[oc] / bsf);
        float a = bsf * bns[oc];
        As[oc] = a;
        Cs[oc] = fmaf(bint, a, bnb[oc]);
    }
    for (int i = tid; i < 2 * TI; i += 256) tile[i] = 0.f;
    float acc[16];
    #pragma unroll
    for (int i = 0; i < 16; ++i) acc[i] = 0.f;
    const float* ib = inp + (long)blockIdx.x * 2 * 32 * PIX;
    for (int ph = 0; ph < 4; ++ph) {
        __syncthreads();
        for (int i = tid; i < NELT; i += 256) {
            int im = i / (8 * PIX);
            int r  = i % (8 * PIX);
            int ci = r / PIX;
            int px = r % PIX;
            int iy = px / HIN, ix = px % HIN;
            tile[(im * 8 + ci) * (ROWS * RS) + (iy + 1) * RS + (ix + 1)] =
                quantv(ib[(long)(im * 32 + ph * 8 + ci) * PIX + px], sf);
        }
        for (int i = tid; i < 2304; i += 256) {
            int oc = i / 72, k = i - oc * 72;
            wlds[k * 36 + oc] = wi[oc * 288 + ph * 72 + k];
        }
        __syncthreads();
        const float* tb = tile + imgl * TI;
        #pragma unroll 2
        for (int ci = 0; ci < 8; ++ci) {
            float win[3][WINW];
            #pragma unroll
            for (int ky = 0; ky < 3; ++ky) {
                const float* rp = tb + ci * (ROWS * RS) + (S * h + ky) * RS + S * 4 * c;
                #pragma unroll
                for (int d = 0; d < ND; ++d)
                    *(float4*)&win[ky][4 * d] = *(const float4*)&rp[4 * d];
            }
            #pragma unroll
            for (int ky = 0; ky < 3; ++ky)
                #pragma unroll
                for (int kx = 0; kx < 3; ++kx) {
                    int j = ky * 3 + kx;
                    float4 wv = *(const float4*)&wlds[(ci * 9 + j) * 36 + ocg * 4];
                    float wvf[4] = {wv.x, wv.y, wv.z, wv.w};
                    #pragma unroll
                    for (int k = 0; k < 4; ++k)
                        #pragma unroll
                        for (int px = 0; px < 4; ++px)
                            acc[k * 4 + px] = fmaf(win[ky][S * px + kx], wvf[k], acc[k * 4 + px]);
                }
        }
    }
    float lmax = 0.f;
    long imgg = (long)blockIdx.x * 2 + imgl;
    #pragma unroll
    for (int k = 0; k < 4; ++k) {
        int oc = ocg * 4 + k;
        float A = As[oc], C = Cs[oc];
        float4 r;
        float* rp = &r.x;
        #pragma unroll
        for (int px = 0; px < 4; ++px) {
            float y = fmaf(acc[k * 4 + px], A, C);
            rp[px] = y;
            lmax = fmaxf(lmax, fabsf(y));
        }
        *(float4*)&out[(imgg * 32 + oc) * 64 + h * 8 + c * 4] = r;
    }
    block_max_atomic(lmax, mout);
}

// ---------------- linear 2048->10 per image ----------------
__global__ __launch_bounds__(256) void k_fc(
    const float* __restrict__ act, const float* __restrict__ wdi,
    const float* __restrict__ wsfd, const float* __restrict__ bd,
    const unsigned* __restrict__ umax, float* __restrict__ logits) {
    int b = blockIdx.x;
    float sf = get_sf(umax, 5);
    const float* ab = act + (long)b * 2048;
    float acc[10] = {0.f, 0.f, 0.f, 0.f, 0.f, 0.f, 0.f, 0.f, 0.f, 0.f};
    #pragma unroll
    for (int k = 0; k < 8; ++k) {
        int j = threadIdx.x + 256 * k;
        float q = quantv(ab[j], sf);
        #pragma unroll
        for (int c = 0; c < 10; ++c) acc[c] = fmaf(q, wdi[c * 2048 + j], acc[c]);
    }
    #pragma unroll
    for (int c = 0; c < 10; ++c)
        #pragma unroll
        for (int o = 32; o; o >>= 1) acc[c] += __shfl_down(acc[c], o, 64);
    __shared__ float red[4][10];
    int wid = threadIdx.x >> 6;
    if ((threadIdx.x & 63) == 0)
        #pragma unroll
        for (int c = 0; c < 10; ++c) red[wid][c] = acc[c];
    __syncthreads();
    if (threadIdx.x < 10) {
        int c = threadIdx.x;
        float s = red[0][c] + red[1][c] + red[2][c] + red[3][c];
        float bsf = wsfd[c] * sf;
        float bint = rintf(bd[c] / bsf);
        logits[b * 10 + c] = (s + bint) * bsf;
    }
}

// ---------------- softmax over batch axis (dim 0) ----------------
__global__ __launch_bounds__(256) void k_softmax(const float* __restrict__ logits, float* __restrict__ out) {
    int c = blockIdx.x;
    float v[4];
    #pragma unroll
    for (int k = 0; k < 4; ++k) v[k] = logits[(threadIdx.x + 256 * k) * 10 + c];
    float mx = fmaxf(fmaxf(v[0], v[1]), fmaxf(v[2], v[3]));
    __shared__ float redm[4];
    __shared__ float reds[4];
    #pragma unroll
    for (int o = 32; o; o >>= 1) mx = fmaxf(mx, __shfl_down(mx, o, 64));
    if ((threadIdx.x & 63) == 0) redm[threadIdx.x >> 6] = mx;
    __syncthreads();
    mx = fmaxf(fmaxf(redm[0], redm[1]), fmaxf(redm[2], redm[3]));
    float e[4], s = 0.f;
    #pragma unroll
    for (int k = 0; k < 4; ++k) { e[k] = expf(v[k] - mx); s += e[k]; }
    #pragma unroll
    for (int o = 32; o; o >>= 1) s += __shfl_down(s, o, 64);
    if ((threadIdx.x & 63) == 0) reds[threadIdx.x >> 6] = s;
    __syncthreads();
    s = reds[0] + reds[1] + reds[2] + reds[3];
    #pragma unroll
    for (int k = 0; k < 4; ++k) out[(threadIdx.x + 256 * k) * 10 + c] = e[k] / s;
}

extern "C" void kernel_launch(void* const* d_in, const int* in_sizes, int n_in,
                              void* d_out, int out_size, void* d_ws, size_t ws_size,
                              hipStream_t stream) {
    (void)in_sizes; (void)n_in; (void)out_size; (void)ws_size;
    const float* x = (const float*)d_in[0];
    const float *w[5], *bia[5], *g[5], *bb[5], *m[5], *v[5];
    for (int i = 0; i < 5; ++i) {
        w[i]   = (const float*)d_in[1 + 6 * i + 0];
        bia[i] = (const float*)d_in[1 + 6 * i + 1];
        g[i]   = (const float*)d_in[1 + 6 * i + 2];
        bb[i]  = (const float*)d_in[1 + 6 * i + 3];
        m[i]   = (const float*)d_in[1 + 6 * i + 4];
        v[i]   = (const float*)d_in[1 + 6 * i + 5];
    }
    const float* wd = (const float*)d_in[31];
    const float* bd = (const float*)d_in[32];
    float* ws = (float*)d_ws;
    unsigned* umax = (unsigned*)ws;
    float* out = (float*)d_out;

    float* wsf0 = ws + OFF_WSF0; float* bns0 = ws + OFF_BNS0; float* bnb0 = ws + OFF_BNB0; float* w0i = ws + OFF_W0I;
    float* wsf1 = ws + OFF_WSF1; float* bns1 = ws + OFF_BNS1; float* bnb1 = ws + OFF_BNB1; float* w1i = ws + OFF_W1I;
    float* wsf2 = ws + OFF_WSF2; float* bns2 = ws + OFF_BNS2; float* bnb2 = ws + OFF_BNB2; float* w2i = ws + OFF_W2I;
    float* wsf3 = ws + OFF_WSF3; float* bns3 = ws + OFF_BNS3; float* bnb3 = ws + OFF_BNB3; float* w3i = ws + OFF_W3I;
    float* wsf4 = ws + OFF_WSF4; float* bns4 = ws + OFF_BNS4; float* bnb4 = ws + OFF_BNB4; float* w4i = ws + OFF_W4I;
    float* wsfd = ws + OFF_WSFD; float* wdi = ws + OFF_WDI;
    float* logits = ws + OFF_LOG;
    float* actA = ws + ACT_A_OFF;   // act2 / act4
    float* actB = ws + ACT_B_OFF;   // act1 / act3

    PrepAll pa;
    pa.umax = umax;
    const float* ww[6] = {w[0], w[1], w[2], w[3], w[4], wd};
    float* wsfp[6] = {wsf0, wsf1, wsf2, wsf3, wsf4, wsfd};
    float* wip[6]  = {w0i, w1i, w2i, w3i, w4i, wdi};
    float* bnsp[6] = {bns0, bns1, bns2, bns3, bns4, nullptr};
    float* bnbp[6] = {bnb0, bnb1, bnb2, bnb3, bnb4, nullptr};
    int Ks[6] = {27, 32, 36, 288, 288, 2048};
    for (int i = 0; i < 6; ++i) {
        pa.e[i].w = ww[i];
        pa.e[i].g = (i < 5) ? g[i] : nullptr;
        pa.e[i].bb = (i < 5) ? bb[i] : nullptr;
        pa.e[i].m = (i < 5) ? m[i] : nullptr;
        pa.e[i].v = (i < 5) ? v[i] : nullptr;
        pa.e[i].wsf = wsfp[i];
        pa.e[i].wint = wip[i];
        pa.e[i].bns = bnsp[i];
        pa.e[i].bnb = bnbp[i];
        pa.e[i].K = Ks[i];
        pa.e[i].has_bn = (i < 5) ? 1 : 0;
    }

    hipLaunchKernelGGL(k_prep_all, dim3(143), dim3(256), 0, stream, pa);
    hipLaunchKernelGGL(k_absmax, dim3(256), dim3(256), 0, stream,
                       (const float4*)x, 1024 * 3 * 32 * 32 / 4, umax + 0);
    hipLaunchKernelGGL(k_conv0maxN, dim3(2048), dim3(256), 0, stream,
                       x, w0i, wsf0, bia[0], bns0, bnb0, umax, umax + 1);
    hipLaunchKernelGGL(k_conv01n, dim3(512), dim3(256), 0, stream,
                       x, w0i, wsf0, bia[0], bns0, bnb0,
                       w1i, wsf1, bia[1], bns1, bnb1, umax, umax + 2, actB);
    hipLaunchKernelGGL(k_conv2c, dim3(1024), dim3(256), 0, stream,
                       actB, w2i, wsf2, bia[2], bns2, bnb2, umax, umax + 3, actA);
    hipLaunchKernelGGL((k_conv34b<16, 2>), dim3(512), dim3(256), 0, stream,
                       actA, w3i, wsf3, bia[3], bns3, bnb3, umax, 3, umax + 4, actB);
    hipLaunchKernelGGL((k_conv34b<8, 1>),  dim3(512), dim3(256), 0, stream,
                       actB, w4i, wsf4, bia[4], bns4, bnb4, umax, 4, umax + 5, actA);
    hipLaunchKernelGGL(k_fc, dim3(1024), dim3(256), 0, stream, actA, wdi, wsfd, bd, umax, logits);
    hipLaunchKernelGGL(k_softmax, dim3(10), dim3(256), 0, stream, logits, out);
}